// Round 2
// baseline (626.798 us; speedup 1.0000x reference)
//
#include <hip/hip_runtime.h>
#include <hip/hip_bf16.h>
#include <math.h>

#define N_NODES 20000
#define N_EDGES 320000
#define DIM 512
#define HEADS 4
#define DHEAD 128
#define NEG_SLOPE 0.2f

typedef __attribute__((ext_vector_type(8))) short short8;
typedef __attribute__((ext_vector_type(8))) __bf16 bf16x8;
typedef __attribute__((ext_vector_type(4))) float f32x4;

static __device__ __forceinline__ unsigned short f32_to_bf16(float f) {
    union { float f; unsigned u; } v; v.f = f;
    unsigned u = v.u;
    u += 0x7FFFu + ((u >> 16) & 1u);   // round-to-nearest-even
    return (unsigned short)(u >> 16);
}
static __device__ __forceinline__ float bf16_to_f32(unsigned short s) {
    union { unsigned u; float f; } v; v.u = ((unsigned)s) << 16;
    return v.f;
}

// ---------------- CSR build ----------------
__global__ void k_hist(const int* __restrict__ dst, int* __restrict__ counts) {
    int e = blockIdx.x * blockDim.x + threadIdx.x;
    if (e >= N_EDGES) return;
    atomicAdd(&counts[dst[e]], 1);
}

__global__ void k_scan(const int* __restrict__ counts, int* __restrict__ offsets,
                       int* __restrict__ cursor) {
    __shared__ int lds[1024];
    int t = threadIdx.x;
    const int CH = (N_NODES + 1023) / 1024;   // 20
    int base = t * CH;
    int sum = 0;
    for (int j = 0; j < CH; j++) {
        int i = base + j;
        if (i < N_NODES) sum += counts[i];
    }
    lds[t] = sum;
    __syncthreads();
    for (int off = 1; off < 1024; off <<= 1) {
        int other = (t >= off) ? lds[t - off] : 0;
        __syncthreads();
        lds[t] += other;
        __syncthreads();
    }
    int excl = lds[t] - sum;
    int run = excl;
    for (int j = 0; j < CH; j++) {
        int i = base + j;
        if (i < N_NODES) {
            offsets[i] = run;
            cursor[i] = run;
            run += counts[i];
        }
    }
    if (t == 0) offsets[N_NODES] = N_EDGES;
}

__global__ void k_fill(const int* __restrict__ src, const int* __restrict__ dst,
                       int* __restrict__ cursor, int* __restrict__ csr_src) {
    int e = blockIdx.x * blockDim.x + threadIdx.x;
    if (e >= N_EDGES) return;
    int d = dst[e];
    int p = atomicAdd(&cursor[d], 1);
    csr_src[p] = src[e];
}

// ---------------- split casts ----------------
// f32 -> hi(bf16) + lo(bf16), x ~= hi + lo
__global__ void k_cast_split(const float* __restrict__ in,
                             unsigned short* __restrict__ hi,
                             unsigned short* __restrict__ lo, int n8) {
    int i = blockIdx.x * blockDim.x + threadIdx.x;
    if (i >= n8) return;
    const float4* p = reinterpret_cast<const float4*>(in) + (size_t)i * 2;
    float4 a = p[0], b = p[1];
    float f[8] = {a.x, a.y, a.z, a.w, b.x, b.y, b.z, b.w};
    short8 oh, ol;
#pragma unroll
    for (int j = 0; j < 8; j++) {
        unsigned short h = f32_to_bf16(f[j]);
        oh[j] = (short)h;
        ol[j] = (short)f32_to_bf16(f[j] - bf16_to_f32(h));
    }
    *reinterpret_cast<short8*>(hi + (size_t)i * 8) = oh;
    *reinterpret_cast<short8*>(lo + (size_t)i * 8) = ol;
}

// W: (H, D, DH) f32 -> Bt_{hi,lo}: [col][k] bf16, col=h*128+f, k over D
__global__ void k_transW(const float* __restrict__ W,
                         unsigned short* __restrict__ Bhi,
                         unsigned short* __restrict__ Blo) {
    int id = blockIdx.x * blockDim.x + threadIdx.x;
    if (id >= 512 * 64) return;
    int col = id >> 6;
    int kg = id & 63;
    int h = col >> 7;
    int f = col & 127;
    short8 oh, ol;
#pragma unroll
    for (int j = 0; j < 8; j++) {
        int k = kg * 8 + j;
        float w = W[(size_t)h * DIM * DHEAD + (size_t)k * DHEAD + f];
        unsigned short hb = f32_to_bf16(w);
        oh[j] = (short)hb;
        ol[j] = (short)f32_to_bf16(w - bf16_to_f32(hb));
    }
    *reinterpret_cast<short8*>(Bhi + (size_t)col * DIM + kg * 8) = oh;
    *reinterpret_cast<short8*>(Blo + (size_t)col * DIM + kg * 8) = ol;
}

// ---------------- GEMM (split bf16 ~ f32) + fused attention logits ----------------
// H[m][c] = sum_k A[m][k]*Bt[c][k];  als[m][h] += H[m][head-cols]·a_src, ald likewise
__global__ __launch_bounds__(256) void k_gemm3(const unsigned short* __restrict__ Ahi,
                                               const unsigned short* __restrict__ Alo,
                                               const unsigned short* __restrict__ Bhi,
                                               const unsigned short* __restrict__ Blo,
                                               const float* __restrict__ avec,
                                               unsigned short* __restrict__ Hout,
                                               float* __restrict__ als,
                                               float* __restrict__ ald) {
    int bid = blockIdx.x;                 // 2500 blocks
    int rb = bid >> 1, cg = bid & 1;
    int wid = threadIdx.x >> 6, lane = threadIdx.x & 63;
    int m0 = rb * 16;
    int n0 = cg * 256 + wid * 64;
    int lr = lane & 15;
    int kq = lane >> 4;

    f32x4 z = {0.f, 0.f, 0.f, 0.f};
    f32x4 acc[4];
    acc[0] = z; acc[1] = z; acc[2] = z; acc[3] = z;

    const short8* Aph = reinterpret_cast<const short8*>(Ahi + (size_t)(m0 + lr) * DIM) + kq;
    const short8* Apl = reinterpret_cast<const short8*>(Alo + (size_t)(m0 + lr) * DIM) + kq;
    const short8* Bph = reinterpret_cast<const short8*>(Bhi + (size_t)(n0 + lr) * DIM) + kq;
    const short8* Bpl = reinterpret_cast<const short8*>(Blo + (size_t)(n0 + lr) * DIM) + kq;

#pragma unroll 2
    for (int kk = 0; kk < 16; kk++) {
        bf16x8 ah = __builtin_bit_cast(bf16x8, Aph[kk * 4]);
        bf16x8 al = __builtin_bit_cast(bf16x8, Apl[kk * 4]);
#pragma unroll
        for (int t = 0; t < 4; t++) {
            bf16x8 bh = __builtin_bit_cast(bf16x8, Bph[t * 1024 + kk * 4]);
            bf16x8 bl = __builtin_bit_cast(bf16x8, Bpl[t * 1024 + kk * 4]);
            acc[t] = __builtin_amdgcn_mfma_f32_16x16x32_bf16(ah, bh, acc[t], 0, 0, 0);
            acc[t] = __builtin_amdgcn_mfma_f32_16x16x32_bf16(ah, bl, acc[t], 0, 0, 0);
            acc[t] = __builtin_amdgcn_mfma_f32_16x16x32_bf16(al, bh, acc[t], 0, 0, 0);
        }
    }

    // store bf16 h for the gather stage
    int orow = kq * 4;
#pragma unroll
    for (int t = 0; t < 4; t++) {
#pragma unroll
        for (int r = 0; r < 4; r++) {
            int row = m0 + orow + r;
            int col = n0 + t * 16 + lr;
            Hout[(size_t)row * DIM + col] = f32_to_bf16(acc[t][r]);
        }
    }

    // fused attention logits from f32 accumulators
    int head = n0 >> 7;                 // 64 cols always within one head
    int fbase = n0 & 127;               // 0 or 64
    const float* asrc = avec + head * 2 * DHEAD;
    const float* adst = asrc + DHEAD;
    float ps[4] = {0.f, 0.f, 0.f, 0.f};
    float pd[4] = {0.f, 0.f, 0.f, 0.f};
#pragma unroll
    for (int t = 0; t < 4; t++) {
        int f = fbase + t * 16 + lr;
        float As = asrc[f];
        float Ad = adst[f];
#pragma unroll
        for (int r = 0; r < 4; r++) {
            ps[r] += acc[t][r] * As;
            pd[r] += acc[t][r] * Ad;
        }
    }
#pragma unroll
    for (int off = 1; off < 16; off <<= 1) {
#pragma unroll
        for (int r = 0; r < 4; r++) {
            ps[r] += __shfl_xor(ps[r], off);
            pd[r] += __shfl_xor(pd[r], off);
        }
    }
    if (lr == 0) {
#pragma unroll
        for (int r = 0; r < 4; r++) {
            int row = m0 + orow + r;
            atomicAdd(&als[row * 4 + head], ps[r]);
            atomicAdd(&ald[row * 4 + head], pd[r]);
        }
    }
}

// ---------------- per-node softmax + aggregation + bias + ELU + residual ----------------
#define ONLINE(mh, sh, scv)                                       \
    {                                                             \
        float sc_ = (scv);                                        \
        sc_ = sc_ > 0.f ? sc_ : NEG_SLOPE * sc_;                  \
        float nm_ = fmaxf(mh, sc_);                               \
        sh = sh * __expf(mh - nm_) + __expf(sc_ - nm_);           \
        mh = nm_;                                                 \
    }

#define COMBINE(mh, sh, off)                                      \
    {                                                             \
        float om_ = __shfl_xor(mh, off);                          \
        float os_ = __shfl_xor(sh, off);                          \
        float nm_ = fmaxf(mh, om_);                               \
        sh = sh * __expf(mh - nm_) + os_ * __expf(om_ - nm_);     \
        mh = nm_;                                                 \
    }

__global__ __launch_bounds__(256) void k_agg(const int* __restrict__ offsets,
                                             const int* __restrict__ csr_src,
                                             const float* __restrict__ als,
                                             const float* __restrict__ ald,
                                             const unsigned short* __restrict__ H,
                                             const float* __restrict__ bias,
                                             const float* __restrict__ resid,
                                             float* __restrict__ out_f32,
                                             unsigned short* __restrict__ out_hi,
                                             unsigned short* __restrict__ out_lo) {
    int v = (blockIdx.x * blockDim.x + threadIdx.x) >> 6;
    if (v >= N_NODES) return;
    int lane = threadIdx.x & 63;
    int beg = offsets[v], end = offsets[v + 1];
    int deg = end - beg;
    float4 aldv = *reinterpret_cast<const float4*>(ald + (size_t)v * 4);

    float m0 = -1e30f, m1 = -1e30f, m2 = -1e30f, m3 = -1e30f;
    float s0 = 0.f, s1 = 0.f, s2 = 0.f, s3 = 0.f;
    for (int i = lane; i < deg; i += 64) {
        int u = csr_src[beg + i];
        float4 as = *reinterpret_cast<const float4*>(als + (size_t)u * 4);
        ONLINE(m0, s0, as.x + aldv.x);
        ONLINE(m1, s1, as.y + aldv.y);
        ONLINE(m2, s2, as.z + aldv.z);
        ONLINE(m3, s3, as.w + aldv.w);
    }
    for (int off = 1; off < 64; off <<= 1) {
        COMBINE(m0, s0, off);
        COMBINE(m1, s1, off);
        COMBINE(m2, s2, off);
        COMBINE(m3, s3, off);
    }
    float i0 = 1.f / (s0 + 1e-16f), i1 = 1.f / (s1 + 1e-16f);
    float i2 = 1.f / (s2 + 1e-16f), i3 = 1.f / (s3 + 1e-16f);

    int hd = lane >> 4;
    float mh = hd == 0 ? m0 : hd == 1 ? m1 : hd == 2 ? m2 : m3;
    float ih = hd == 0 ? i0 : hd == 1 ? i1 : hd == 2 ? i2 : i3;
    float adh = hd == 0 ? aldv.x : hd == 1 ? aldv.y : hd == 2 ? aldv.z : aldv.w;

    float acc[8] = {0.f, 0.f, 0.f, 0.f, 0.f, 0.f, 0.f, 0.f};
    for (int i = 0; i < deg; i++) {
        int u = csr_src[beg + i];
        float4 as = *reinterpret_cast<const float4*>(als + (size_t)u * 4);
        float av = hd == 0 ? as.x : hd == 1 ? as.y : hd == 2 ? as.z : as.w;
        float sc = av + adh;
        sc = sc > 0.f ? sc : NEG_SLOPE * sc;
        float wgt = __expf(sc - mh) * ih;
        short8 hv = *reinterpret_cast<const short8*>(H + (size_t)u * DIM + lane * 8);
#pragma unroll
        for (int j = 0; j < 8; j++) acc[j] += wgt * bf16_to_f32((unsigned short)hv[j]);
    }

    int col = lane * 8;
    const float4* rp = reinterpret_cast<const float4*>(resid + (size_t)v * DIM + col);
    float4 r1 = rp[0], r2 = rp[1];
    float o[8];
#pragma unroll
    for (int j = 0; j < 8; j++) {
        float t = acc[j] + bias[col + j];
        t = t > 0.f ? t : expm1f(t);
        o[j] = t;
    }
    o[0] += r1.x; o[1] += r1.y; o[2] += r1.z; o[3] += r1.w;
    o[4] += r2.x; o[5] += r2.y; o[6] += r2.z; o[7] += r2.w;
    float4 w1 = {o[0], o[1], o[2], o[3]};
    float4 w2 = {o[4], o[5], o[6], o[7]};
    float4* op = reinterpret_cast<float4*>(out_f32 + (size_t)v * DIM + col);
    op[0] = w1;
    op[1] = w2;
    if (out_hi) {
        short8 oh, ol;
#pragma unroll
        for (int j = 0; j < 8; j++) {
            unsigned short hb = f32_to_bf16(o[j]);
            oh[j] = (short)hb;
            ol[j] = (short)f32_to_bf16(o[j] - bf16_to_f32(hb));
        }
        *reinterpret_cast<short8*>(out_hi + (size_t)v * DIM + col) = oh;
        *reinterpret_cast<short8*>(out_lo + (size_t)v * DIM + col) = ol;
    }
}

extern "C" void kernel_launch(void* const* d_in, const int* in_sizes, int n_in,
                              void* d_out, int out_size, void* d_ws, size_t ws_size,
                              hipStream_t stream) {
    const float* x = (const float*)d_in[0];
    const int* ei = (const int*)d_in[1];
    const int* src = ei;
    const int* dst = ei + N_EDGES;
    const float* W1 = (const float*)d_in[5];
    const float* a1 = (const float*)d_in[6];
    const float* b1 = (const float*)d_in[7];
    const float* W2 = (const float*)d_in[8];
    const float* a2 = (const float*)d_in[9];
    const float* b2 = (const float*)d_in[10];

    char* ws = (char*)d_ws;
    size_t off = 0;
    auto alloc = [&](size_t bytes) -> void* {
        void* p = ws + off;
        off += (bytes + 255) & ~(size_t)255;
        return p;
    };
    unsigned short* xhi  = (unsigned short*)alloc((size_t)N_NODES * DIM * 2);
    unsigned short* xlo  = (unsigned short*)alloc((size_t)N_NODES * DIM * 2);
    unsigned short* h    = (unsigned short*)alloc((size_t)N_NODES * DIM * 2);
    float* x1            = (float*)alloc((size_t)N_NODES * DIM * 4);
    float* als           = (float*)alloc((size_t)N_NODES * 8 * 4);  // als | ald contiguous
    float* ald           = als + (size_t)N_NODES * 4;
    unsigned short* B1h  = (unsigned short*)alloc((size_t)DIM * DIM * 2);
    unsigned short* B1l  = (unsigned short*)alloc((size_t)DIM * DIM * 2);
    unsigned short* B2h  = (unsigned short*)alloc((size_t)DIM * DIM * 2);
    unsigned short* B2l  = (unsigned short*)alloc((size_t)DIM * DIM * 2);
    int* offsets         = (int*)alloc((size_t)(N_NODES + 1) * 4);
    int* cursor          = (int*)alloc((size_t)N_NODES * 4);
    int* counts          = (int*)alloc((size_t)N_NODES * 4);
    int* csr_src         = (int*)alloc((size_t)N_EDGES * 4);

    // CSR build (shared by both layers)
    hipMemsetAsync(counts, 0, (size_t)N_NODES * 4, stream);
    k_hist<<<(N_EDGES + 255) / 256, 256, 0, stream>>>(dst, counts);
    k_scan<<<1, 1024, 0, stream>>>(counts, offsets, cursor);
    k_fill<<<(N_EDGES + 255) / 256, 256, 0, stream>>>(src, dst, cursor, csr_src);

    // casts / weight prep
    k_cast_split<<<(N_NODES * DIM / 8 + 255) / 256, 256, 0, stream>>>(x, xhi, xlo, N_NODES * DIM / 8);
    k_transW<<<(512 * 64 + 255) / 256, 256, 0, stream>>>(W1, B1h, B1l);
    k_transW<<<(512 * 64 + 255) / 256, 256, 0, stream>>>(W2, B2h, B2l);

    // ---- layer 1 ----
    hipMemsetAsync(als, 0, (size_t)N_NODES * 8 * 4, stream);
    k_gemm3<<<2500, 256, 0, stream>>>(xhi, xlo, B1h, B1l, a1, h, als, ald);
    k_agg<<<(N_NODES + 3) / 4, 256, 0, stream>>>(offsets, csr_src, als, ald, h, b1, x, x1, xhi, xlo);

    // ---- layer 2 ----
    hipMemsetAsync(als, 0, (size_t)N_NODES * 8 * 4, stream);
    k_gemm3<<<2500, 256, 0, stream>>>(xhi, xlo, B2h, B2l, a2, h, als, ald);
    k_agg<<<(N_NODES + 3) / 4, 256, 0, stream>>>(offsets, csr_src, als, ald, h, b2, x1, (float*)d_out, nullptr, nullptr);
}

// Round 3
// 393.228 us; speedup vs baseline: 1.5940x; 1.5940x over previous
//
#include <hip/hip_runtime.h>
#include <hip/hip_bf16.h>
#include <math.h>

#define N_NODES 20000
#define N_EDGES 320000
#define DIM 512
#define HEADS 4
#define DHEAD 128
#define NEG_SLOPE 0.2f
#define BM 128
#define BK 64

typedef __attribute__((ext_vector_type(8))) short short8;
typedef __attribute__((ext_vector_type(8))) __bf16 bf16x8;
typedef __attribute__((ext_vector_type(4))) float f32x4;

static __device__ __forceinline__ unsigned short f32_to_bf16(float f) {
    union { float f; unsigned u; } v; v.f = f;
    unsigned u = v.u;
    u += 0x7FFFu + ((u >> 16) & 1u);   // round-to-nearest-even
    return (unsigned short)(u >> 16);
}
static __device__ __forceinline__ float bf16_to_f32(unsigned short s) {
    union { unsigned u; float f; } v; v.u = ((unsigned)s) << 16;
    return v.f;
}

static __device__ __forceinline__ void gl_lds16(const unsigned short* g, unsigned short* l) {
    __builtin_amdgcn_global_load_lds(
        (const __attribute__((address_space(1))) unsigned int*)g,
        (__attribute__((address_space(3))) unsigned int*)l, 16, 0, 0);
}

// ---------------- CSR build ----------------
__global__ void k_hist(const int* __restrict__ dst, int* __restrict__ counts) {
    int e = blockIdx.x * blockDim.x + threadIdx.x;
    if (e >= N_EDGES) return;
    atomicAdd(&counts[dst[e]], 1);
}

__global__ void k_scan(const int* __restrict__ counts, int* __restrict__ offsets,
                       int* __restrict__ cursor) {
    __shared__ int lds[1024];
    int t = threadIdx.x;
    const int CH = (N_NODES + 1023) / 1024;   // 20
    int base = t * CH;
    int sum = 0;
    for (int j = 0; j < CH; j++) {
        int i = base + j;
        if (i < N_NODES) sum += counts[i];
    }
    lds[t] = sum;
    __syncthreads();
    for (int off = 1; off < 1024; off <<= 1) {
        int other = (t >= off) ? lds[t - off] : 0;
        __syncthreads();
        lds[t] += other;
        __syncthreads();
    }
    int excl = lds[t] - sum;
    int run = excl;
    for (int j = 0; j < CH; j++) {
        int i = base + j;
        if (i < N_NODES) {
            offsets[i] = run;
            cursor[i] = run;
            run += counts[i];
        }
    }
    if (t == 0) offsets[N_NODES] = N_EDGES;
}

__global__ void k_fill(const int* __restrict__ src, const int* __restrict__ dst,
                       int* __restrict__ cursor, int* __restrict__ csr_src) {
    int e = blockIdx.x * blockDim.x + threadIdx.x;
    if (e >= N_EDGES) return;
    int d = dst[e];
    int p = atomicAdd(&cursor[d], 1);
    csr_src[p] = src[e];
}

// ---------------- split casts ----------------
__global__ void k_cast_split(const float* __restrict__ in,
                             unsigned short* __restrict__ hi,
                             unsigned short* __restrict__ lo, int n8) {
    int i = blockIdx.x * blockDim.x + threadIdx.x;
    if (i >= n8) return;
    const float4* p = reinterpret_cast<const float4*>(in) + (size_t)i * 2;
    float4 a = p[0], b = p[1];
    float f[8] = {a.x, a.y, a.z, a.w, b.x, b.y, b.z, b.w};
    short8 oh, ol;
#pragma unroll
    for (int j = 0; j < 8; j++) {
        unsigned short h = f32_to_bf16(f[j]);
        oh[j] = (short)h;
        ol[j] = (short)f32_to_bf16(f[j] - bf16_to_f32(h));
    }
    *reinterpret_cast<short8*>(hi + (size_t)i * 8) = oh;
    *reinterpret_cast<short8*>(lo + (size_t)i * 8) = ol;
}

// W: (H, D, DH) f32 -> Bt_{hi,lo}: [col][k] bf16, col=h*128+f, k over D
__global__ void k_transW(const float* __restrict__ W,
                         unsigned short* __restrict__ Bhi,
                         unsigned short* __restrict__ Blo) {
    int id = blockIdx.x * blockDim.x + threadIdx.x;
    if (id >= 512 * 64) return;
    int col = id >> 6;
    int kg = id & 63;
    int h = col >> 7;
    int f = col & 127;
    short8 oh, ol;
#pragma unroll
    for (int j = 0; j < 8; j++) {
        int k = kg * 8 + j;
        float w = W[(size_t)h * DIM * DHEAD + (size_t)k * DHEAD + f];
        unsigned short hb = f32_to_bf16(w);
        oh[j] = (short)hb;
        ol[j] = (short)f32_to_bf16(w - bf16_to_f32(hb));
    }
    *reinterpret_cast<short8*>(Bhi + (size_t)col * DIM + kg * 8) = oh;
    *reinterpret_cast<short8*>(Blo + (size_t)col * DIM + kg * 8) = ol;
}

// ---------------- LDS-tiled split-bf16 GEMM + fused attention logits ----------------
// C[m][c] = sum_k A[m][k]*Bt[c][k], A=Ahi+Alo, Bt=Bhi+Blo (3 MFMA products).
// Block: BM=128 rows x 128 cols (one head), 4 waves in 2x2, BK=64, 64KB LDS single-buffer.
// LDS slot swizzle: 8 slots of 16B per 128B row; phys = log ^ (row&7). Linear LDS dest for
// global_load_lds + inverse-swizzled global source + swizzled ds_read (both-sides rule).
#define MFMA(a, b, c) __builtin_amdgcn_mfma_f32_16x16x32_bf16(a, b, c, 0, 0, 0)

__global__ __launch_bounds__(256, 2) void k_gemm_t(const unsigned short* __restrict__ Ahi,
                                                   const unsigned short* __restrict__ Alo,
                                                   const unsigned short* __restrict__ Bhi,
                                                   const unsigned short* __restrict__ Blo,
                                                   const float* __restrict__ avec,
                                                   unsigned short* __restrict__ Hout,
                                                   float* __restrict__ als,
                                                   float* __restrict__ ald) {
    __shared__ unsigned short lds[32768];   // 64 KB: Ah | Al | Bh | Bl (8192 shorts each)
    const int tid = threadIdx.x;
    const int bid = blockIdx.x;             // 157*4
    const int mb = bid >> 2, nb = bid & 3;
    const int m0 = mb * BM, n0 = nb * 128;
    const int lane = tid & 63, wid = tid >> 6;
    const int wm = wid >> 1, wn = wid & 1;
    const int lr = lane & 15, kq = lane >> 4;

    f32x4 acc[4][4];
#pragma unroll
    for (int i = 0; i < 4; i++)
#pragma unroll
        for (int j = 0; j < 4; j++) acc[i][j] = (f32x4){0.f, 0.f, 0.f, 0.f};

#pragma unroll 1
    for (int t = 0; t < 8; t++) {
        const int k0 = t * BK;
        // ---- stage 64KB (A hi/lo tile + B hi/lo tile) ----
#pragma unroll
        for (int it = 0; it < 4; it++) {
            int c = it * 256 + tid;
            int row = c >> 3;
            int sl = (c & 7) ^ (row & 7);            // inverse-swizzled source slot
            int ar = m0 + row;
            ar = ar < N_NODES ? ar : N_NODES - 1;
            const unsigned short* ga = Ahi + (size_t)ar * DIM + k0 + sl * 8;
            const unsigned short* gal = Alo + (size_t)ar * DIM + k0 + sl * 8;
            const unsigned short* gb = Bhi + (size_t)(n0 + row) * DIM + k0 + sl * 8;
            const unsigned short* gbl = Blo + (size_t)(n0 + row) * DIM + k0 + sl * 8;
            unsigned short* lb = lds + (size_t)(it * 256 + (tid & 192)) * 8;  // wave-uniform
            gl_lds16(ga, lb);
            gl_lds16(gal, lb + 8192);
            gl_lds16(gb, lb + 16384);
            gl_lds16(gbl, lb + 24576);
        }
        asm volatile("s_waitcnt vmcnt(0)" ::: "memory");
        __syncthreads();

        // ---- compute this K-tile ----
#pragma unroll
        for (int ks = 0; ks < 2; ks++) {
            bf16x8 ah[4], alo[4], bh[4], blo[4];
#pragma unroll
            for (int tm = 0; tm < 4; tm++) {
                int row = wm * 64 + tm * 16 + lr;
                int sp = (ks * 4 + kq) ^ (row & 7);
                int off = row * 64 + sp * 8;
                ah[tm] = __builtin_bit_cast(bf16x8, *reinterpret_cast<const short8*>(lds + off));
                alo[tm] = __builtin_bit_cast(bf16x8, *reinterpret_cast<const short8*>(lds + 8192 + off));
            }
#pragma unroll
            for (int tn = 0; tn < 4; tn++) {
                int col = wn * 64 + tn * 16 + lr;
                int sp = (ks * 4 + kq) ^ (col & 7);
                int off = col * 64 + sp * 8;
                bh[tn] = __builtin_bit_cast(bf16x8, *reinterpret_cast<const short8*>(lds + 16384 + off));
                blo[tn] = __builtin_bit_cast(bf16x8, *reinterpret_cast<const short8*>(lds + 24576 + off));
            }
#pragma unroll
            for (int tm = 0; tm < 4; tm++)
#pragma unroll
                for (int tn = 0; tn < 4; tn++) {
                    acc[tm][tn] = MFMA(ah[tm], bh[tn], acc[tm][tn]);
                    acc[tm][tn] = MFMA(ah[tm], blo[tn], acc[tm][tn]);
                    acc[tm][tn] = MFMA(alo[tm], bh[tn], acc[tm][tn]);
                }
        }
        if (t < 7) __syncthreads();
    }

    // ---- store bf16 h ----
#pragma unroll
    for (int tm = 0; tm < 4; tm++)
#pragma unroll
        for (int tn = 0; tn < 4; tn++) {
            int col = n0 + wn * 64 + tn * 16 + lr;
#pragma unroll
            for (int r = 0; r < 4; r++) {
                int row = m0 + wm * 64 + tm * 16 + kq * 4 + r;
                if (row < N_NODES) Hout[(size_t)row * DIM + col] = f32_to_bf16(acc[tm][tn][r]);
            }
        }

    // ---- fused attention logits from f32 accumulators (exact h) ----
    const float* asrc = avec + nb * 2 * DHEAD;
    const float* adst = asrc + DHEAD;
    float ps[4][4], pd[4][4];
#pragma unroll
    for (int tm = 0; tm < 4; tm++)
#pragma unroll
        for (int r = 0; r < 4; r++) { ps[tm][r] = 0.f; pd[tm][r] = 0.f; }
#pragma unroll
    for (int tn = 0; tn < 4; tn++) {
        int f = wn * 64 + tn * 16 + lr;
        float As = asrc[f];
        float Ad = adst[f];
#pragma unroll
        for (int tm = 0; tm < 4; tm++)
#pragma unroll
            for (int r = 0; r < 4; r++) {
                ps[tm][r] += acc[tm][tn][r] * As;
                pd[tm][r] += acc[tm][tn][r] * Ad;
            }
    }
#pragma unroll
    for (int off = 1; off < 16; off <<= 1)
#pragma unroll
        for (int tm = 0; tm < 4; tm++)
#pragma unroll
            for (int r = 0; r < 4; r++) {
                ps[tm][r] += __shfl_xor(ps[tm][r], off);
                pd[tm][r] += __shfl_xor(pd[tm][r], off);
            }
    if (lr == 0) {
#pragma unroll
        for (int tm = 0; tm < 4; tm++)
#pragma unroll
            for (int r = 0; r < 4; r++) {
                int row = m0 + wm * 64 + tm * 16 + kq * 4 + r;
                if (row < N_NODES) {
                    atomicAdd(&als[row * 4 + nb], ps[tm][r]);
                    atomicAdd(&ald[row * 4 + nb], pd[tm][r]);
                }
            }
    }
}

// ---------------- per-node softmax + aggregation + bias + ELU + residual ----------------
#define ONLINE(mh, sh, scv)                                       \
    {                                                             \
        float sc_ = (scv);                                        \
        sc_ = sc_ > 0.f ? sc_ : NEG_SLOPE * sc_;                  \
        float nm_ = fmaxf(mh, sc_);                               \
        sh = sh * __expf(mh - nm_) + __expf(sc_ - nm_);           \
        mh = nm_;                                                 \
    }

#define COMBINE(mh, sh, off)                                      \
    {                                                             \
        float om_ = __shfl_xor(mh, off);                          \
        float os_ = __shfl_xor(sh, off);                          \
        float nm_ = fmaxf(mh, om_);                               \
        sh = sh * __expf(mh - nm_) + os_ * __expf(om_ - nm_);     \
        mh = nm_;                                                 \
    }

__global__ __launch_bounds__(256) void k_agg(const int* __restrict__ offsets,
                                             const int* __restrict__ csr_src,
                                             const float* __restrict__ als,
                                             const float* __restrict__ ald,
                                             const unsigned short* __restrict__ H,
                                             const float* __restrict__ bias,
                                             const float* __restrict__ resid,
                                             float* __restrict__ out_f32,
                                             unsigned short* __restrict__ out_hi,
                                             unsigned short* __restrict__ out_lo) {
    int v = (blockIdx.x * blockDim.x + threadIdx.x) >> 6;
    if (v >= N_NODES) return;
    int lane = threadIdx.x & 63;
    int beg = offsets[v], end = offsets[v + 1];
    int deg = end - beg;
    float4 aldv = *reinterpret_cast<const float4*>(ald + (size_t)v * 4);

    float m0 = -1e30f, m1 = -1e30f, m2 = -1e30f, m3 = -1e30f;
    float s0 = 0.f, s1 = 0.f, s2 = 0.f, s3 = 0.f;
    for (int i = lane; i < deg; i += 64) {
        int u = csr_src[beg + i];
        float4 as = *reinterpret_cast<const float4*>(als + (size_t)u * 4);
        ONLINE(m0, s0, as.x + aldv.x);
        ONLINE(m1, s1, as.y + aldv.y);
        ONLINE(m2, s2, as.z + aldv.z);
        ONLINE(m3, s3, as.w + aldv.w);
    }
    for (int off = 1; off < 64; off <<= 1) {
        COMBINE(m0, s0, off);
        COMBINE(m1, s1, off);
        COMBINE(m2, s2, off);
        COMBINE(m3, s3, off);
    }
    float i0 = 1.f / (s0 + 1e-16f), i1 = 1.f / (s1 + 1e-16f);
    float i2 = 1.f / (s2 + 1e-16f), i3 = 1.f / (s3 + 1e-16f);

    int hd = lane >> 4;
    float mh = hd == 0 ? m0 : hd == 1 ? m1 : hd == 2 ? m2 : m3;
    float ih = hd == 0 ? i0 : hd == 1 ? i1 : hd == 2 ? i2 : i3;
    float adh = hd == 0 ? aldv.x : hd == 1 ? aldv.y : hd == 2 ? aldv.z : aldv.w;

    float acc[8] = {0.f, 0.f, 0.f, 0.f, 0.f, 0.f, 0.f, 0.f};
    for (int i = 0; i < deg; i++) {
        int u = csr_src[beg + i];
        float4 as = *reinterpret_cast<const float4*>(als + (size_t)u * 4);
        float av = hd == 0 ? as.x : hd == 1 ? as.y : hd == 2 ? as.z : as.w;
        float sc = av + adh;
        sc = sc > 0.f ? sc : NEG_SLOPE * sc;
        float wgt = __expf(sc - mh) * ih;
        short8 hv = *reinterpret_cast<const short8*>(H + (size_t)u * DIM + lane * 8);
#pragma unroll
        for (int j = 0; j < 8; j++) acc[j] += wgt * bf16_to_f32((unsigned short)hv[j]);
    }

    int col = lane * 8;
    const float4* rp = reinterpret_cast<const float4*>(resid + (size_t)v * DIM + col);
    float4 r1 = rp[0], r2 = rp[1];
    float o[8];
#pragma unroll
    for (int j = 0; j < 8; j++) {
        float t = acc[j] + bias[col + j];
        t = t > 0.f ? t : expm1f(t);
        o[j] = t;
    }
    o[0] += r1.x; o[1] += r1.y; o[2] += r1.z; o[3] += r1.w;
    o[4] += r2.x; o[5] += r2.y; o[6] += r2.z; o[7] += r2.w;
    float4 w1 = {o[0], o[1], o[2], o[3]};
    float4 w2 = {o[4], o[5], o[6], o[7]};
    float4* op = reinterpret_cast<float4*>(out_f32 + (size_t)v * DIM + col);
    op[0] = w1;
    op[1] = w2;
    if (out_hi) {
        short8 oh, ol;
#pragma unroll
        for (int j = 0; j < 8; j++) {
            unsigned short hb = f32_to_bf16(o[j]);
            oh[j] = (short)hb;
            ol[j] = (short)f32_to_bf16(o[j] - bf16_to_f32(hb));
        }
        *reinterpret_cast<short8*>(out_hi + (size_t)v * DIM + col) = oh;
        *reinterpret_cast<short8*>(out_lo + (size_t)v * DIM + col) = ol;
    }
}

extern "C" void kernel_launch(void* const* d_in, const int* in_sizes, int n_in,
                              void* d_out, int out_size, void* d_ws, size_t ws_size,
                              hipStream_t stream) {
    const float* x = (const float*)d_in[0];
    const int* ei = (const int*)d_in[1];
    const int* src = ei;
    const int* dst = ei + N_EDGES;
    const float* W1 = (const float*)d_in[5];
    const float* a1 = (const float*)d_in[6];
    const float* b1 = (const float*)d_in[7];
    const float* W2 = (const float*)d_in[8];
    const float* a2 = (const float*)d_in[9];
    const float* b2 = (const float*)d_in[10];

    char* ws = (char*)d_ws;
    size_t off = 0;
    auto alloc = [&](size_t bytes) -> void* {
        void* p = ws + off;
        off += (bytes + 255) & ~(size_t)255;
        return p;
    };
    unsigned short* xhi  = (unsigned short*)alloc((size_t)N_NODES * DIM * 2);
    unsigned short* xlo  = (unsigned short*)alloc((size_t)N_NODES * DIM * 2);
    unsigned short* h    = (unsigned short*)alloc((size_t)N_NODES * DIM * 2);
    float* x1            = (float*)alloc((size_t)N_NODES * DIM * 4);
    float* als           = (float*)alloc((size_t)N_NODES * 8 * 4);  // als | ald contiguous
    float* ald           = als + (size_t)N_NODES * 4;
    unsigned short* B1h  = (unsigned short*)alloc((size_t)DIM * DIM * 2);
    unsigned short* B1l  = (unsigned short*)alloc((size_t)DIM * DIM * 2);
    unsigned short* B2h  = (unsigned short*)alloc((size_t)DIM * DIM * 2);
    unsigned short* B2l  = (unsigned short*)alloc((size_t)DIM * DIM * 2);
    int* offsets         = (int*)alloc((size_t)(N_NODES + 1) * 4);
    int* cursor          = (int*)alloc((size_t)N_NODES * 4);
    int* counts          = (int*)alloc((size_t)N_NODES * 4);
    int* csr_src         = (int*)alloc((size_t)N_EDGES * 4);

    // CSR build (shared by both layers)
    hipMemsetAsync(counts, 0, (size_t)N_NODES * 4, stream);
    k_hist<<<(N_EDGES + 255) / 256, 256, 0, stream>>>(dst, counts);
    k_scan<<<1, 1024, 0, stream>>>(counts, offsets, cursor);
    k_fill<<<(N_EDGES + 255) / 256, 256, 0, stream>>>(src, dst, cursor, csr_src);

    // casts / weight prep
    k_cast_split<<<(N_NODES * DIM / 8 + 255) / 256, 256, 0, stream>>>(x, xhi, xlo, N_NODES * DIM / 8);
    k_transW<<<(512 * 64 + 255) / 256, 256, 0, stream>>>(W1, B1h, B1l);
    k_transW<<<(512 * 64 + 255) / 256, 256, 0, stream>>>(W2, B2h, B2l);

    const int GEMM_BLOCKS = ((N_NODES + BM - 1) / BM) * 4;   // 157 * 4

    // ---- layer 1 ----
    hipMemsetAsync(als, 0, (size_t)N_NODES * 8 * 4, stream);
    k_gemm_t<<<GEMM_BLOCKS, 256, 0, stream>>>(xhi, xlo, B1h, B1l, a1, h, als, ald);
    k_agg<<<(N_NODES + 3) / 4, 256, 0, stream>>>(offsets, csr_src, als, ald, h, b1, x, x1, xhi, xlo);

    // ---- layer 2 ----
    hipMemsetAsync(als, 0, (size_t)N_NODES * 8 * 4, stream);
    k_gemm_t<<<GEMM_BLOCKS, 256, 0, stream>>>(xhi, xlo, B2h, B2l, a2, h, als, ald);
    k_agg<<<(N_NODES + 3) / 4, 256, 0, stream>>>(offsets, csr_src, als, ald, h, b2, x1, (float*)d_out, nullptr, nullptr);
}

// Round 4
// 343.450 us; speedup vs baseline: 1.8250x; 1.1449x over previous
//
#include <hip/hip_runtime.h>
#include <hip/hip_bf16.h>
#include <math.h>

#define N_NODES 20000
#define N_EDGES 320000
#define DIM 512
#define HEADS 4
#define DHEAD 128
#define NEG_SLOPE 0.2f
#define BM 128
#define BK 64

typedef __attribute__((ext_vector_type(8))) short short8;
typedef __attribute__((ext_vector_type(8))) __bf16 bf16x8;
typedef __attribute__((ext_vector_type(4))) float f32x4;

static __device__ __forceinline__ unsigned short f32_to_bf16(float f) {
    union { float f; unsigned u; } v; v.f = f;
    unsigned u = v.u;
    u += 0x7FFFu + ((u >> 16) & 1u);   // round-to-nearest-even
    return (unsigned short)(u >> 16);
}
static __device__ __forceinline__ float bf16_to_f32(unsigned short s) {
    union { unsigned u; float f; } v; v.u = ((unsigned)s) << 16;
    return v.f;
}
static __device__ __forceinline__ float bits_f32(unsigned u) {
    union { unsigned u; float f; } v; v.u = u;
    return v.f;
}

static __device__ __forceinline__ void gl_lds16(const unsigned short* g, unsigned short* l) {
    __builtin_amdgcn_global_load_lds(
        (const __attribute__((address_space(1))) unsigned int*)g,
        (__attribute__((address_space(3))) unsigned int*)l, 16, 0, 0);
}

// ---------------- CSR build ----------------
__global__ void k_hist(const int* __restrict__ dst, int* __restrict__ counts) {
    int e = blockIdx.x * blockDim.x + threadIdx.x;
    if (e >= N_EDGES) return;
    atomicAdd(&counts[dst[e]], 1);
}

__global__ void k_scan(const int* __restrict__ counts, int* __restrict__ offsets,
                       int* __restrict__ cursor) {
    __shared__ int lds[1024];
    int t = threadIdx.x;
    const int CH = (N_NODES + 1023) / 1024;   // 20
    int base = t * CH;
    int sum = 0;
    for (int j = 0; j < CH; j++) {
        int i = base + j;
        if (i < N_NODES) sum += counts[i];
    }
    lds[t] = sum;
    __syncthreads();
    for (int off = 1; off < 1024; off <<= 1) {
        int other = (t >= off) ? lds[t - off] : 0;
        __syncthreads();
        lds[t] += other;
        __syncthreads();
    }
    int excl = lds[t] - sum;
    int run = excl;
    for (int j = 0; j < CH; j++) {
        int i = base + j;
        if (i < N_NODES) {
            offsets[i] = run;
            cursor[i] = run;
            run += counts[i];
        }
    }
    if (t == 0) offsets[N_NODES] = N_EDGES;
}

__global__ void k_fill(const int* __restrict__ src, const int* __restrict__ dst,
                       int* __restrict__ cursor, int* __restrict__ csr_src) {
    int e = blockIdx.x * blockDim.x + threadIdx.x;
    if (e >= N_EDGES) return;
    int d = dst[e];
    int p = atomicAdd(&cursor[d], 1);
    csr_src[p] = src[e];
}

// ---------------- split casts ----------------
__global__ void k_cast_split(const float* __restrict__ in,
                             unsigned short* __restrict__ hi,
                             unsigned short* __restrict__ lo, int n8) {
    int i = blockIdx.x * blockDim.x + threadIdx.x;
    if (i >= n8) return;
    const float4* p = reinterpret_cast<const float4*>(in) + (size_t)i * 2;
    float4 a = p[0], b = p[1];
    float f[8] = {a.x, a.y, a.z, a.w, b.x, b.y, b.z, b.w};
    short8 oh, ol;
#pragma unroll
    for (int j = 0; j < 8; j++) {
        unsigned short h = f32_to_bf16(f[j]);
        oh[j] = (short)h;
        ol[j] = (short)f32_to_bf16(f[j] - bf16_to_f32(h));
    }
    *reinterpret_cast<short8*>(hi + (size_t)i * 8) = oh;
    *reinterpret_cast<short8*>(lo + (size_t)i * 8) = ol;
}

// W: (H, D, DH) f32 -> Bt_{hi,lo}: [col][k] bf16, col=h*128+f, k over D
__global__ void k_transW(const float* __restrict__ W,
                         unsigned short* __restrict__ Bhi,
                         unsigned short* __restrict__ Blo) {
    int id = blockIdx.x * blockDim.x + threadIdx.x;
    if (id >= 512 * 64) return;
    int col = id >> 6;
    int kg = id & 63;
    int h = col >> 7;
    int f = col & 127;
    short8 oh, ol;
#pragma unroll
    for (int j = 0; j < 8; j++) {
        int k = kg * 8 + j;
        float w = W[(size_t)h * DIM * DHEAD + (size_t)k * DHEAD + f];
        unsigned short hb = f32_to_bf16(w);
        oh[j] = (short)hb;
        ol[j] = (short)f32_to_bf16(w - bf16_to_f32(hb));
    }
    *reinterpret_cast<short8*>(Bhi + (size_t)col * DIM + kg * 8) = oh;
    *reinterpret_cast<short8*>(Blo + (size_t)col * DIM + kg * 8) = ol;
}

// ---------------- LDS-tiled split-bf16 GEMM + fused attention logits ----------------
#define MFMA(a, b, c) __builtin_amdgcn_mfma_f32_16x16x32_bf16(a, b, c, 0, 0, 0)

__global__ __launch_bounds__(256, 2) void k_gemm_t(const unsigned short* __restrict__ Ahi,
                                                   const unsigned short* __restrict__ Alo,
                                                   const unsigned short* __restrict__ Bhi,
                                                   const unsigned short* __restrict__ Blo,
                                                   const float* __restrict__ avec,
                                                   unsigned short* __restrict__ Hout,
                                                   float* __restrict__ als,
                                                   float* __restrict__ ald) {
    __shared__ unsigned short lds[32768];   // 64 KB: Ah | Al | Bh | Bl (8192 shorts each)
    const int tid = threadIdx.x;
    const int bid = blockIdx.x;             // 157*4
    const int mb = bid >> 2, nb = bid & 3;
    const int m0 = mb * BM, n0 = nb * 128;
    const int lane = tid & 63, wid = tid >> 6;
    const int wm = wid >> 1, wn = wid & 1;
    const int lr = lane & 15, kq = lane >> 4;

    f32x4 acc[4][4];
#pragma unroll
    for (int i = 0; i < 4; i++)
#pragma unroll
        for (int j = 0; j < 4; j++) acc[i][j] = (f32x4){0.f, 0.f, 0.f, 0.f};

#pragma unroll 1
    for (int t = 0; t < 8; t++) {
        const int k0 = t * BK;
#pragma unroll
        for (int it = 0; it < 4; it++) {
            int c = it * 256 + tid;
            int row = c >> 3;
            int sl = (c & 7) ^ (row & 7);            // inverse-swizzled source slot
            int ar = m0 + row;
            ar = ar < N_NODES ? ar : N_NODES - 1;
            const unsigned short* ga = Ahi + (size_t)ar * DIM + k0 + sl * 8;
            const unsigned short* gal = Alo + (size_t)ar * DIM + k0 + sl * 8;
            const unsigned short* gb = Bhi + (size_t)(n0 + row) * DIM + k0 + sl * 8;
            const unsigned short* gbl = Blo + (size_t)(n0 + row) * DIM + k0 + sl * 8;
            unsigned short* lb = lds + (size_t)(it * 256 + (tid & 192)) * 8;  // wave-uniform
            gl_lds16(ga, lb);
            gl_lds16(gal, lb + 8192);
            gl_lds16(gb, lb + 16384);
            gl_lds16(gbl, lb + 24576);
        }
        asm volatile("s_waitcnt vmcnt(0)" ::: "memory");
        __syncthreads();

#pragma unroll
        for (int ks = 0; ks < 2; ks++) {
            bf16x8 ah[4], alo[4], bh[4], blo[4];
#pragma unroll
            for (int tm = 0; tm < 4; tm++) {
                int row = wm * 64 + tm * 16 + lr;
                int sp = (ks * 4 + kq) ^ (row & 7);
                int off = row * 64 + sp * 8;
                ah[tm] = __builtin_bit_cast(bf16x8, *reinterpret_cast<const short8*>(lds + off));
                alo[tm] = __builtin_bit_cast(bf16x8, *reinterpret_cast<const short8*>(lds + 8192 + off));
            }
#pragma unroll
            for (int tn = 0; tn < 4; tn++) {
                int col = wn * 64 + tn * 16 + lr;
                int sp = (ks * 4 + kq) ^ (col & 7);
                int off = col * 64 + sp * 8;
                bh[tn] = __builtin_bit_cast(bf16x8, *reinterpret_cast<const short8*>(lds + 16384 + off));
                blo[tn] = __builtin_bit_cast(bf16x8, *reinterpret_cast<const short8*>(lds + 24576 + off));
            }
#pragma unroll
            for (int tm = 0; tm < 4; tm++)
#pragma unroll
                for (int tn = 0; tn < 4; tn++) {
                    acc[tm][tn] = MFMA(ah[tm], bh[tn], acc[tm][tn]);
                    acc[tm][tn] = MFMA(ah[tm], blo[tn], acc[tm][tn]);
                    acc[tm][tn] = MFMA(alo[tm], bh[tn], acc[tm][tn]);
                }
        }
        if (t < 7) __syncthreads();
    }

#pragma unroll
    for (int tm = 0; tm < 4; tm++)
#pragma unroll
        for (int tn = 0; tn < 4; tn++) {
            int col = n0 + wn * 64 + tn * 16 + lr;
#pragma unroll
            for (int r = 0; r < 4; r++) {
                int row = m0 + wm * 64 + tm * 16 + kq * 4 + r;
                if (row < N_NODES) Hout[(size_t)row * DIM + col] = f32_to_bf16(acc[tm][tn][r]);
            }
        }

    const float* asrc = avec + nb * 2 * DHEAD;
    const float* adst = asrc + DHEAD;
    float ps[4][4], pd[4][4];
#pragma unroll
    for (int tm = 0; tm < 4; tm++)
#pragma unroll
        for (int r = 0; r < 4; r++) { ps[tm][r] = 0.f; pd[tm][r] = 0.f; }
#pragma unroll
    for (int tn = 0; tn < 4; tn++) {
        int f = wn * 64 + tn * 16 + lr;
        float As = asrc[f];
        float Ad = adst[f];
#pragma unroll
        for (int tm = 0; tm < 4; tm++)
#pragma unroll
            for (int r = 0; r < 4; r++) {
                ps[tm][r] += acc[tm][tn][r] * As;
                pd[tm][r] += acc[tm][tn][r] * Ad;
            }
    }
#pragma unroll
    for (int off = 1; off < 16; off <<= 1)
#pragma unroll
        for (int tm = 0; tm < 4; tm++)
#pragma unroll
            for (int r = 0; r < 4; r++) {
                ps[tm][r] += __shfl_xor(ps[tm][r], off);
                pd[tm][r] += __shfl_xor(pd[tm][r], off);
            }
    if (lr == 0) {
#pragma unroll
        for (int tm = 0; tm < 4; tm++)
#pragma unroll
            for (int r = 0; r < 4; r++) {
                int row = m0 + wm * 64 + tm * 16 + kq * 4 + r;
                if (row < N_NODES) {
                    atomicAdd(&als[row * 4 + nb], ps[tm][r]);
                    atomicAdd(&ald[row * 4 + nb], pd[tm][r]);
                }
            }
    }
}

// ---------------- single-pass softmax-free aggregation ----------------
// wave = (node v, half hf); lane covers 4 cols at c0 = hf*256 + lane*4 (one head).
// alpha = exp(leaky(e)) / sum(exp(leaky(e)))  (no max subtraction: |e| <= ~45 << 88)
#define EDGE_STEP(uu, ee, w0, w1)                                           \
    {                                                                       \
        float sc_ = (ee) + aldh;                                            \
        sc_ = fmaxf(sc_, NEG_SLOPE * sc_);                                  \
        float w_ = __expf(sc_);                                             \
        s += w_;                                                            \
        acc0 += w_ * bits_f32((w0) << 16);                                  \
        acc1 += w_ * bits_f32((w0) & 0xFFFF0000u);                          \
        acc2 += w_ * bits_f32((w1) << 16);                                  \
        acc3 += w_ * bits_f32((w1) & 0xFFFF0000u);                          \
    }

__global__ __launch_bounds__(256) void k_agg(const int* __restrict__ offsets,
                                             const int* __restrict__ csr_src,
                                             const float* __restrict__ als,
                                             const float* __restrict__ ald,
                                             const unsigned short* __restrict__ H,
                                             const float* __restrict__ bias,
                                             const float* __restrict__ resid,
                                             float* __restrict__ out_f32,
                                             unsigned short* __restrict__ out_hi,
                                             unsigned short* __restrict__ out_lo) {
    int gw = (blockIdx.x * blockDim.x + threadIdx.x) >> 6;
    if (gw >= N_NODES * 2) return;
    int v = gw >> 1;
    int hf = gw & 1;
    int lane = threadIdx.x & 63;
    int c0 = hf * 256 + lane * 4;
    int hd = c0 >> 7;

    int beg = offsets[v], deg = offsets[v + 1] - beg;
    float aldh = ald[v * 4 + hd];
    const int* cp = csr_src + beg;

    float acc0 = 0.f, acc1 = 0.f, acc2 = 0.f, acc3 = 0.f, s = 0.f;
    int i = 0;
    for (; i + 4 <= deg; i += 4) {
        int u0 = cp[i], u1 = cp[i + 1], u2 = cp[i + 2], u3 = cp[i + 3];
        float e0 = als[u0 * 4 + hd];
        float e1 = als[u1 * 4 + hd];
        float e2 = als[u2 * 4 + hd];
        float e3 = als[u3 * 4 + hd];
        uint2 h0 = *reinterpret_cast<const uint2*>(H + (size_t)u0 * DIM + c0);
        uint2 h1 = *reinterpret_cast<const uint2*>(H + (size_t)u1 * DIM + c0);
        uint2 h2 = *reinterpret_cast<const uint2*>(H + (size_t)u2 * DIM + c0);
        uint2 h3 = *reinterpret_cast<const uint2*>(H + (size_t)u3 * DIM + c0);
        EDGE_STEP(u0, e0, h0.x, h0.y);
        EDGE_STEP(u1, e1, h1.x, h1.y);
        EDGE_STEP(u2, e2, h2.x, h2.y);
        EDGE_STEP(u3, e3, h3.x, h3.y);
    }
    for (; i < deg; i++) {
        int u0 = cp[i];
        float e0 = als[u0 * 4 + hd];
        uint2 h0 = *reinterpret_cast<const uint2*>(H + (size_t)u0 * DIM + c0);
        EDGE_STEP(u0, e0, h0.x, h0.y);
    }

    float inv = deg > 0 ? 1.0f / s : 0.f;
    float4 bv = *reinterpret_cast<const float4*>(bias + c0);
    float4 rv = *reinterpret_cast<const float4*>(resid + (size_t)v * DIM + c0);
    float o0 = acc0 * inv + bv.x;
    float o1 = acc1 * inv + bv.y;
    float o2 = acc2 * inv + bv.z;
    float o3 = acc3 * inv + bv.w;
    o0 = o0 > 0.f ? o0 : expm1f(o0);
    o1 = o1 > 0.f ? o1 : expm1f(o1);
    o2 = o2 > 0.f ? o2 : expm1f(o2);
    o3 = o3 > 0.f ? o3 : expm1f(o3);
    o0 += rv.x; o1 += rv.y; o2 += rv.z; o3 += rv.w;
    float4 ov = {o0, o1, o2, o3};
    *reinterpret_cast<float4*>(out_f32 + (size_t)v * DIM + c0) = ov;
    if (out_hi) {
        unsigned short hb0 = f32_to_bf16(o0), hb1 = f32_to_bf16(o1);
        unsigned short hb2 = f32_to_bf16(o2), hb3 = f32_to_bf16(o3);
        ushort4 oh = {hb0, hb1, hb2, hb3};
        ushort4 ol = {f32_to_bf16(o0 - bf16_to_f32(hb0)), f32_to_bf16(o1 - bf16_to_f32(hb1)),
                      f32_to_bf16(o2 - bf16_to_f32(hb2)), f32_to_bf16(o3 - bf16_to_f32(hb3))};
        *reinterpret_cast<ushort4*>(out_hi + (size_t)v * DIM + c0) = oh;
        *reinterpret_cast<ushort4*>(out_lo + (size_t)v * DIM + c0) = ol;
    }
}

extern "C" void kernel_launch(void* const* d_in, const int* in_sizes, int n_in,
                              void* d_out, int out_size, void* d_ws, size_t ws_size,
                              hipStream_t stream) {
    const float* x = (const float*)d_in[0];
    const int* ei = (const int*)d_in[1];
    const int* src = ei;
    const int* dst = ei + N_EDGES;
    const float* W1 = (const float*)d_in[5];
    const float* a1 = (const float*)d_in[6];
    const float* b1 = (const float*)d_in[7];
    const float* W2 = (const float*)d_in[8];
    const float* a2 = (const float*)d_in[9];
    const float* b2 = (const float*)d_in[10];

    char* ws = (char*)d_ws;
    size_t off = 0;
    auto alloc = [&](size_t bytes) -> void* {
        void* p = ws + off;
        off += (bytes + 255) & ~(size_t)255;
        return p;
    };
    unsigned short* xhi  = (unsigned short*)alloc((size_t)N_NODES * DIM * 2);
    unsigned short* xlo  = (unsigned short*)alloc((size_t)N_NODES * DIM * 2);
    unsigned short* h    = (unsigned short*)alloc((size_t)N_NODES * DIM * 2);
    float* x1            = (float*)alloc((size_t)N_NODES * DIM * 4);
    float* als           = (float*)alloc((size_t)N_NODES * 8 * 4);  // als | ald contiguous
    float* ald           = als + (size_t)N_NODES * 4;
    unsigned short* B1h  = (unsigned short*)alloc((size_t)DIM * DIM * 2);
    unsigned short* B1l  = (unsigned short*)alloc((size_t)DIM * DIM * 2);
    unsigned short* B2h  = (unsigned short*)alloc((size_t)DIM * DIM * 2);
    unsigned short* B2l  = (unsigned short*)alloc((size_t)DIM * DIM * 2);
    int* offsets         = (int*)alloc((size_t)(N_NODES + 1) * 4);
    int* cursor          = (int*)alloc((size_t)N_NODES * 4);
    int* counts          = (int*)alloc((size_t)N_NODES * 4);
    int* csr_src         = (int*)alloc((size_t)N_EDGES * 4);

    // CSR build (shared by both layers)
    hipMemsetAsync(counts, 0, (size_t)N_NODES * 4, stream);
    k_hist<<<(N_EDGES + 255) / 256, 256, 0, stream>>>(dst, counts);
    k_scan<<<1, 1024, 0, stream>>>(counts, offsets, cursor);
    k_fill<<<(N_EDGES + 255) / 256, 256, 0, stream>>>(src, dst, cursor, csr_src);

    // casts / weight prep
    k_cast_split<<<(N_NODES * DIM / 8 + 255) / 256, 256, 0, stream>>>(x, xhi, xlo, N_NODES * DIM / 8);
    k_transW<<<(512 * 64 + 255) / 256, 256, 0, stream>>>(W1, B1h, B1l);
    k_transW<<<(512 * 64 + 255) / 256, 256, 0, stream>>>(W2, B2h, B2l);

    const int GEMM_BLOCKS = ((N_NODES + BM - 1) / BM) * 4;   // 157 * 4
    const int AGG_BLOCKS = (N_NODES * 2 + 3) / 4;            // 10000

    // ---- layer 1 ----
    hipMemsetAsync(als, 0, (size_t)N_NODES * 8 * 4, stream);
    k_gemm_t<<<GEMM_BLOCKS, 256, 0, stream>>>(xhi, xlo, B1h, B1l, a1, h, als, ald);
    k_agg<<<AGG_BLOCKS, 256, 0, stream>>>(offsets, csr_src, als, ald, h, b1, x, x1, xhi, xlo);

    // ---- layer 2 ----
    hipMemsetAsync(als, 0, (size_t)N_NODES * 8 * 4, stream);
    k_gemm_t<<<GEMM_BLOCKS, 256, 0, stream>>>(xhi, xlo, B2h, B2l, a2, h, als, ald);
    k_agg<<<AGG_BLOCKS, 256, 0, stream>>>(offsets, csr_src, als, ald, h, b2, x1, (float*)d_out, nullptr, nullptr);
}

// Round 5
// 343.255 us; speedup vs baseline: 1.8260x; 1.0006x over previous
//
#include <hip/hip_runtime.h>
#include <hip/hip_bf16.h>
#include <math.h>

#define N_NODES 20000
#define N_EDGES 320000
#define DIM 512
#define HEADS 4
#define DHEAD 128
#define NEG_SLOPE 0.2f
#define BM 128
#define BK 32

typedef __attribute__((ext_vector_type(8))) short short8;
typedef __attribute__((ext_vector_type(8))) __bf16 bf16x8;
typedef __attribute__((ext_vector_type(4))) float f32x4;

static __device__ __forceinline__ unsigned short f32_to_bf16(float f) {
    union { float f; unsigned u; } v; v.f = f;
    unsigned u = v.u;
    u += 0x7FFFu + ((u >> 16) & 1u);   // round-to-nearest-even
    return (unsigned short)(u >> 16);
}
static __device__ __forceinline__ float bf16_to_f32(unsigned short s) {
    union { unsigned u; float f; } v; v.u = ((unsigned)s) << 16;
    return v.f;
}
static __device__ __forceinline__ float bits_f32(unsigned u) {
    union { unsigned u; float f; } v; v.u = u;
    return v.f;
}

static __device__ __forceinline__ void gl_lds16(const unsigned short* g, unsigned short* l) {
    __builtin_amdgcn_global_load_lds(
        (const __attribute__((address_space(1))) unsigned int*)g,
        (__attribute__((address_space(3))) unsigned int*)l, 16, 0, 0);
}

// ---------------- CSR build ----------------
__global__ void k_hist(const int* __restrict__ dst, int* __restrict__ counts) {
    int e = blockIdx.x * blockDim.x + threadIdx.x;
    if (e >= N_EDGES) return;
    atomicAdd(&counts[dst[e]], 1);
}

__global__ void k_scan(const int* __restrict__ counts, int* __restrict__ offsets,
                       int* __restrict__ cursor) {
    __shared__ int lds[1024];
    int t = threadIdx.x;
    const int CH = (N_NODES + 1023) / 1024;   // 20
    int base = t * CH;
    int sum = 0;
    for (int j = 0; j < CH; j++) {
        int i = base + j;
        if (i < N_NODES) sum += counts[i];
    }
    lds[t] = sum;
    __syncthreads();
    for (int off = 1; off < 1024; off <<= 1) {
        int other = (t >= off) ? lds[t - off] : 0;
        __syncthreads();
        lds[t] += other;
        __syncthreads();
    }
    int excl = lds[t] - sum;
    int run = excl;
    for (int j = 0; j < CH; j++) {
        int i = base + j;
        if (i < N_NODES) {
            offsets[i] = run;
            cursor[i] = run;
            run += counts[i];
        }
    }
    if (t == 0) offsets[N_NODES] = N_EDGES;
}

__global__ void k_fill(const int* __restrict__ src, const int* __restrict__ dst,
                       int* __restrict__ cursor, int* __restrict__ csr_src) {
    int e = blockIdx.x * blockDim.x + threadIdx.x;
    if (e >= N_EDGES) return;
    int d = dst[e];
    int p = atomicAdd(&cursor[d], 1);
    csr_src[p] = src[e];
}

// ---------------- split casts ----------------
__global__ void k_cast_split(const float* __restrict__ in,
                             unsigned short* __restrict__ hi,
                             unsigned short* __restrict__ lo, int n8) {
    int i = blockIdx.x * blockDim.x + threadIdx.x;
    if (i >= n8) return;
    const float4* p = reinterpret_cast<const float4*>(in) + (size_t)i * 2;
    float4 a = p[0], b = p[1];
    float f[8] = {a.x, a.y, a.z, a.w, b.x, b.y, b.z, b.w};
    short8 oh, ol;
#pragma unroll
    for (int j = 0; j < 8; j++) {
        unsigned short h = f32_to_bf16(f[j]);
        oh[j] = (short)h;
        ol[j] = (short)f32_to_bf16(f[j] - bf16_to_f32(h));
    }
    *reinterpret_cast<short8*>(hi + (size_t)i * 8) = oh;
    *reinterpret_cast<short8*>(lo + (size_t)i * 8) = ol;
}

// W: (H, D, DH) f32 -> Bt_{hi,lo}: [col][k] bf16, col=h*128+f, k over D
__global__ void k_transW(const float* __restrict__ W,
                         unsigned short* __restrict__ Bhi,
                         unsigned short* __restrict__ Blo) {
    int id = blockIdx.x * blockDim.x + threadIdx.x;
    if (id >= 512 * 64) return;
    int col = id >> 6;
    int kg = id & 63;
    int h = col >> 7;
    int f = col & 127;
    short8 oh, ol;
#pragma unroll
    for (int j = 0; j < 8; j++) {
        int k = kg * 8 + j;
        float w = W[(size_t)h * DIM * DHEAD + (size_t)k * DHEAD + f];
        unsigned short hb = f32_to_bf16(w);
        oh[j] = (short)hb;
        ol[j] = (short)f32_to_bf16(w - bf16_to_f32(hb));
    }
    *reinterpret_cast<short8*>(Bhi + (size_t)col * DIM + kg * 8) = oh;
    *reinterpret_cast<short8*>(Blo + (size_t)col * DIM + kg * 8) = ol;
}

// ---------------- LDS-tiled split-bf16 GEMM + fused attention logits ----------------
// Double-buffered BK=32 pipeline. Per buffer (32KB): A region 128 rows x 128B
// (slots 0-3 = hi k0..31, slots 4-7 = lo k0..31), then B region likewise.
// phys_slot = log_slot ^ (row&7): linear LDS dest for global_load_lds +
// inverse-swizzled per-lane global source + swizzled ds_read (both-sides rule).
#define MFMA(a, b, c) __builtin_amdgcn_mfma_f32_16x16x32_bf16(a, b, c, 0, 0, 0)

__global__ __launch_bounds__(256, 2) void k_gemm_t(const unsigned short* __restrict__ Ahi,
                                                   const unsigned short* __restrict__ Alo,
                                                   const unsigned short* __restrict__ Bhi,
                                                   const unsigned short* __restrict__ Blo,
                                                   const float* __restrict__ avec,
                                                   unsigned short* __restrict__ Hout,
                                                   float* __restrict__ als,
                                                   float* __restrict__ ald) {
    __shared__ unsigned short lds[32768];   // 64 KB: two 32KB buffers
    const int tid = threadIdx.x;

    // bijective XCD swizzle (nwg=628, round-robin dispatch -> contiguous work per XCD)
    {
    }
    const int orig = blockIdx.x;
    const int xcd = orig & 7;
    const int jj = orig >> 3;
    const int q = 78, r = 4;                 // 628 = 8*78 + 4
    const int wgid = (xcd < r ? xcd * (q + 1) : r * (q + 1) + (xcd - r) * q) + jj;
    const int mb = wgid >> 2, nb = wgid & 3;
    const int m0 = mb * BM, n0 = nb * 128;
    const int lane = tid & 63, wid = tid >> 6;
    const int wm = wid >> 1, wn = wid & 1;
    const int lr = lane & 15, kq = lane >> 4;

    f32x4 acc[4][4];
#pragma unroll
    for (int i = 0; i < 4; i++)
#pragma unroll
        for (int j = 0; j < 4; j++) acc[i][j] = (f32x4){0.f, 0.f, 0.f, 0.f};

    auto STAGE = [&](int t, int bufb) {
#pragma unroll
        for (int it = 0; it < 8; it++) {
            int c = it * 256 + tid;
            int rrow = (c >> 3) & 127;
            int ls = (c & 7) ^ (rrow & 7);           // logical slot for this phys slot
            int koff = t * BK + (ls & 3) * 8;
            const unsigned short* srcp;
            if (it < 4) {                            // A region
                int ar = m0 + rrow;
                ar = ar < N_NODES ? ar : N_NODES - 1;
                srcp = (ls < 4 ? Ahi : Alo) + (size_t)ar * DIM + koff;
            } else {                                 // B region
                srcp = (ls < 4 ? Bhi : Blo) + (size_t)(n0 + rrow) * DIM + koff;
            }
            unsigned short* lb = lds + bufb + (it * 256 + (tid & 192)) * 8;
            gl_lds16(srcp, lb);
        }
    };

    STAGE(0, 0);
    asm volatile("s_waitcnt vmcnt(0)" ::: "memory");
    __syncthreads();

    int cur = 0;
#pragma unroll 1
    for (int t = 0; t < 16; t++) {
        if (t < 15) STAGE(t + 1, (cur ^ 1) << 14);

        const int bufb = cur << 14;
        bf16x8 ah[4], alo[4], bh[4], blo[4];
#pragma unroll
        for (int tm = 0; tm < 4; tm++) {
            int row = wm * 64 + tm * 16 + lr;
            int ph = kq ^ (row & 7);
            const unsigned short* base = lds + bufb + row * 64;
            ah[tm] = __builtin_bit_cast(bf16x8, *reinterpret_cast<const short8*>(base + ph * 8));
            alo[tm] = __builtin_bit_cast(bf16x8, *reinterpret_cast<const short8*>(base + (ph ^ 4) * 8));
        }
#pragma unroll
        for (int tn = 0; tn < 4; tn++) {
            int col = wn * 64 + tn * 16 + lr;
            int ph = kq ^ (col & 7);
            const unsigned short* base = lds + bufb + 8192 + col * 64;
            bh[tn] = __builtin_bit_cast(bf16x8, *reinterpret_cast<const short8*>(base + ph * 8));
            blo[tn] = __builtin_bit_cast(bf16x8, *reinterpret_cast<const short8*>(base + (ph ^ 4) * 8));
        }
#pragma unroll
        for (int tm = 0; tm < 4; tm++)
#pragma unroll
            for (int tn = 0; tn < 4; tn++) {
                acc[tm][tn] = MFMA(ah[tm], bh[tn], acc[tm][tn]);
                acc[tm][tn] = MFMA(ah[tm], blo[tn], acc[tm][tn]);
                acc[tm][tn] = MFMA(alo[tm], bh[tn], acc[tm][tn]);
            }
        if (t < 15) {
            asm volatile("s_waitcnt vmcnt(0)" ::: "memory");
            __syncthreads();
            cur ^= 1;
        }
    }

    // ---- store bf16 h ----
#pragma unroll
    for (int tm = 0; tm < 4; tm++)
#pragma unroll
        for (int tn = 0; tn < 4; tn++) {
            int col = n0 + wn * 64 + tn * 16 + lr;
#pragma unroll
            for (int r4 = 0; r4 < 4; r4++) {
                int row = m0 + wm * 64 + tm * 16 + kq * 4 + r4;
                if (row < N_NODES) Hout[(size_t)row * DIM + col] = f32_to_bf16(acc[tm][tn][r4]);
            }
        }

    // ---- fused attention logits from f32 accumulators (exact h) ----
    const float* asrc = avec + nb * 2 * DHEAD;
    const float* adst = asrc + DHEAD;
    float ps[4][4], pd[4][4];
#pragma unroll
    for (int tm = 0; tm < 4; tm++)
#pragma unroll
        for (int r4 = 0; r4 < 4; r4++) { ps[tm][r4] = 0.f; pd[tm][r4] = 0.f; }
#pragma unroll
    for (int tn = 0; tn < 4; tn++) {
        int f = wn * 64 + tn * 16 + lr;
        float As = asrc[f];
        float Ad = adst[f];
#pragma unroll
        for (int tm = 0; tm < 4; tm++)
#pragma unroll
            for (int r4 = 0; r4 < 4; r4++) {
                ps[tm][r4] += acc[tm][tn][r4] * As;
                pd[tm][r4] += acc[tm][tn][r4] * Ad;
            }
    }
#pragma unroll
    for (int off = 1; off < 16; off <<= 1)
#pragma unroll
        for (int tm = 0; tm < 4; tm++)
#pragma unroll
            for (int r4 = 0; r4 < 4; r4++) {
                ps[tm][r4] += __shfl_xor(ps[tm][r4], off);
                pd[tm][r4] += __shfl_xor(pd[tm][r4], off);
            }
    if (lr == 0) {
#pragma unroll
        for (int tm = 0; tm < 4; tm++)
#pragma unroll
            for (int r4 = 0; r4 < 4; r4++) {
                int row = m0 + wm * 64 + tm * 16 + kq * 4 + r4;
                if (row < N_NODES) {
                    atomicAdd(&als[row * 4 + nb], ps[tm][r4]);
                    atomicAdd(&ald[row * 4 + nb], pd[tm][r4]);
                }
            }
    }
}

// ---------------- single-pass softmax-free aggregation ----------------
// wave = (node v, half hf); lane covers 4 cols at c0 = hf*256 + lane*4 (one head).
// alpha = exp(leaky(e)) / sum(exp(leaky(e)))  (no max subtraction: |e| <= ~45 << 88)
#define EDGE_STEP(uu, ee, w0, w1)                                           \
    {                                                                       \
        float sc_ = (ee) + aldh;                                            \
        sc_ = fmaxf(sc_, NEG_SLOPE * sc_);                                  \
        float w_ = __expf(sc_);                                             \
        s += w_;                                                            \
        acc0 += w_ * bits_f32((w0) << 16);                                  \
        acc1 += w_ * bits_f32((w0) & 0xFFFF0000u);                          \
        acc2 += w_ * bits_f32((w1) << 16);                                  \
        acc3 += w_ * bits_f32((w1) & 0xFFFF0000u);                          \
    }

__global__ __launch_bounds__(256) void k_agg(const int* __restrict__ offsets,
                                             const int* __restrict__ csr_src,
                                             const float* __restrict__ als,
                                             const float* __restrict__ ald,
                                             const unsigned short* __restrict__ H,
                                             const float* __restrict__ bias,
                                             const float* __restrict__ resid,
                                             float* __restrict__ out_f32,
                                             unsigned short* __restrict__ out_hi,
                                             unsigned short* __restrict__ out_lo) {
    int gw = (blockIdx.x * blockDim.x + threadIdx.x) >> 6;
    if (gw >= N_NODES * 2) return;
    int v = gw >> 1;
    int hf = gw & 1;
    int lane = threadIdx.x & 63;
    int c0 = hf * 256 + lane * 4;
    int hd = c0 >> 7;

    int beg = offsets[v], deg = offsets[v + 1] - beg;
    float aldh = ald[v * 4 + hd];
    const int* cp = csr_src + beg;

    float acc0 = 0.f, acc1 = 0.f, acc2 = 0.f, acc3 = 0.f, s = 0.f;
    int i = 0;
    for (; i + 4 <= deg; i += 4) {
        int u0 = cp[i], u1 = cp[i + 1], u2 = cp[i + 2], u3 = cp[i + 3];
        float e0 = als[u0 * 4 + hd];
        float e1 = als[u1 * 4 + hd];
        float e2 = als[u2 * 4 + hd];
        float e3 = als[u3 * 4 + hd];
        uint2 h0 = *reinterpret_cast<const uint2*>(H + (size_t)u0 * DIM + c0);
        uint2 h1 = *reinterpret_cast<const uint2*>(H + (size_t)u1 * DIM + c0);
        uint2 h2 = *reinterpret_cast<const uint2*>(H + (size_t)u2 * DIM + c0);
        uint2 h3 = *reinterpret_cast<const uint2*>(H + (size_t)u3 * DIM + c0);
        EDGE_STEP(u0, e0, h0.x, h0.y);
        EDGE_STEP(u1, e1, h1.x, h1.y);
        EDGE_STEP(u2, e2, h2.x, h2.y);
        EDGE_STEP(u3, e3, h3.x, h3.y);
    }
    for (; i < deg; i++) {
        int u0 = cp[i];
        float e0 = als[u0 * 4 + hd];
        uint2 h0 = *reinterpret_cast<const uint2*>(H + (size_t)u0 * DIM + c0);
        EDGE_STEP(u0, e0, h0.x, h0.y);
    }

    float inv = deg > 0 ? 1.0f / s : 0.f;
    float4 bv = *reinterpret_cast<const float4*>(bias + c0);
    float4 rv = *reinterpret_cast<const float4*>(resid + (size_t)v * DIM + c0);
    float o0 = acc0 * inv + bv.x;
    float o1 = acc1 * inv + bv.y;
    float o2 = acc2 * inv + bv.z;
    float o3 = acc3 * inv + bv.w;
    o0 = o0 > 0.f ? o0 : expm1f(o0);
    o1 = o1 > 0.f ? o1 : expm1f(o1);
    o2 = o2 > 0.f ? o2 : expm1f(o2);
    o3 = o3 > 0.f ? o3 : expm1f(o3);
    o0 += rv.x; o1 += rv.y; o2 += rv.z; o3 += rv.w;
    float4 ov = {o0, o1, o2, o3};
    *reinterpret_cast<float4*>(out_f32 + (size_t)v * DIM + c0) = ov;
    if (out_hi) {
        unsigned short hb0 = f32_to_bf16(o0), hb1 = f32_to_bf16(o1);
        unsigned short hb2 = f32_to_bf16(o2), hb3 = f32_to_bf16(o3);
        ushort4 oh = {hb0, hb1, hb2, hb3};
        ushort4 ol = {f32_to_bf16(o0 - bf16_to_f32(hb0)), f32_to_bf16(o1 - bf16_to_f32(hb1)),
                      f32_to_bf16(o2 - bf16_to_f32(hb2)), f32_to_bf16(o3 - bf16_to_f32(hb3))};
        *reinterpret_cast<ushort4*>(out_hi + (size_t)v * DIM + c0) = oh;
        *reinterpret_cast<ushort4*>(out_lo + (size_t)v * DIM + c0) = ol;
    }
}

extern "C" void kernel_launch(void* const* d_in, const int* in_sizes, int n_in,
                              void* d_out, int out_size, void* d_ws, size_t ws_size,
                              hipStream_t stream) {
    const float* x = (const float*)d_in[0];
    const int* ei = (const int*)d_in[1];
    const int* src = ei;
    const int* dst = ei + N_EDGES;
    const float* W1 = (const float*)d_in[5];
    const float* a1 = (const float*)d_in[6];
    const float* b1 = (const float*)d_in[7];
    const float* W2 = (const float*)d_in[8];
    const float* a2 = (const float*)d_in[9];
    const float* b2 = (const float*)d_in[10];

    char* ws = (char*)d_ws;
    size_t off = 0;
    auto alloc = [&](size_t bytes) -> void* {
        void* p = ws + off;
        off += (bytes + 255) & ~(size_t)255;
        return p;
    };
    unsigned short* xhi  = (unsigned short*)alloc((size_t)N_NODES * DIM * 2);
    unsigned short* xlo  = (unsigned short*)alloc((size_t)N_NODES * DIM * 2);
    unsigned short* h    = (unsigned short*)alloc((size_t)N_NODES * DIM * 2);
    float* x1            = (float*)alloc((size_t)N_NODES * DIM * 4);
    float* als           = (float*)alloc((size_t)N_NODES * 8 * 4);  // als | ald contiguous
    float* ald           = als + (size_t)N_NODES * 4;
    unsigned short* B1h  = (unsigned short*)alloc((size_t)DIM * DIM * 2);
    unsigned short* B1l  = (unsigned short*)alloc((size_t)DIM * DIM * 2);
    unsigned short* B2h  = (unsigned short*)alloc((size_t)DIM * DIM * 2);
    unsigned short* B2l  = (unsigned short*)alloc((size_t)DIM * DIM * 2);
    int* offsets         = (int*)alloc((size_t)(N_NODES + 1) * 4);
    int* cursor          = (int*)alloc((size_t)N_NODES * 4);
    int* counts          = (int*)alloc((size_t)N_NODES * 4);
    int* csr_src         = (int*)alloc((size_t)N_EDGES * 4);

    // CSR build (shared by both layers)
    hipMemsetAsync(counts, 0, (size_t)N_NODES * 4, stream);
    k_hist<<<(N_EDGES + 255) / 256, 256, 0, stream>>>(dst, counts);
    k_scan<<<1, 1024, 0, stream>>>(counts, offsets, cursor);
    k_fill<<<(N_EDGES + 255) / 256, 256, 0, stream>>>(src, dst, cursor, csr_src);

    // casts / weight prep
    k_cast_split<<<(N_NODES * DIM / 8 + 255) / 256, 256, 0, stream>>>(x, xhi, xlo, N_NODES * DIM / 8);
    k_transW<<<(512 * 64 + 255) / 256, 256, 0, stream>>>(W1, B1h, B1l);
    k_transW<<<(512 * 64 + 255) / 256, 256, 0, stream>>>(W2, B2h, B2l);

    const int GEMM_BLOCKS = ((N_NODES + BM - 1) / BM) * 4;   // 157 * 4 = 628
    const int AGG_BLOCKS = (N_NODES * 2 + 3) / 4;            // 10000

    // ---- layer 1 ----
    hipMemsetAsync(als, 0, (size_t)N_NODES * 8 * 4, stream);
    k_gemm_t<<<GEMM_BLOCKS, 256, 0, stream>>>(xhi, xlo, B1h, B1l, a1, h, als, ald);
    k_agg<<<AGG_BLOCKS, 256, 0, stream>>>(offsets, csr_src, als, ald, h, b1, x, x1, xhi, xlo);

    // ---- layer 2 ----
    hipMemsetAsync(als, 0, (size_t)N_NODES * 8 * 4, stream);
    k_gemm_t<<<GEMM_BLOCKS, 256, 0, stream>>>(xhi, xlo, B2h, B2l, a2, h, als, ald);
    k_agg<<<AGG_BLOCKS, 256, 0, stream>>>(offsets, csr_src, als, ald, h, b2, x1, (float*)d_out, nullptr, nullptr);
}